// Round 1
// baseline (581.405 us; speedup 1.0000x reference)
//
#include <hip/hip_runtime.h>

#define N_   16
#define M_   100
#define L_   10000
#define EMB_ 128
#define TL   64    // l-tile per block
#define NT   256   // threads per block (4 waves)

__global__ __launch_bounds__(NT, 2) void attn_fused_kernel(
    const float* __restrict__ self_attn,   // (N, M, EMB)
    const float* __restrict__ self_delta,  // (N, M, L, 4)
    const float* __restrict__ emb_table,   // (L+1, EMB)
    const float* __restrict__ value_w,     // (M)
    float* __restrict__ out)               // (N, L)
{
    // dltw[ll][m] = (sum_d4 self_delta[n][m][l0+ll][d4]) * value_w[m]
    // stride 101: bank = (5*ll + m) % 32 -> 2-way across 64 lanes = conflict-free
    __shared__ float dltw[TL][M_ + 1];
    __shared__ float red[4][TL];
    __shared__ float wsh[M_];

    const int n   = blockIdx.y;
    const int l0  = blockIdx.x * TL;
    const int tid = threadIdx.x;

    if (tid < M_) wsh[tid] = value_w[tid];
    __syncthreads();

    // ---- Phase 1: stage delta*w into LDS (coalesced float4 reads of self_delta) ----
    // 6400 (ll, m) pairs over 256 threads = 25 iterations each.
    const float4* dp = (const float4*)self_delta + (size_t)n * M_ * L_;
    #pragma unroll 5
    for (int it = 0; it < (TL * M_) / NT; ++it) {
        int idx = tid + it * NT;
        int ll  = idx & (TL - 1);
        int m   = idx >> 6;
        int l   = l0 + ll;
        float v = 0.f;
        if (l < L_) {
            float4 d4 = dp[(size_t)m * L_ + l];
            v = (d4.x + d4.y + d4.z + d4.w) * wsh[m];
        }
        dltw[ll][m] = v;
    }
    __syncthreads();

    // ---- Phase 2: q[d] = sum_m attn[n][m][d] * dltw[ll][m], d in 32-chunk per thread ----
    const int ll    = tid & (TL - 1);
    const int chunk = tid >> 6;   // 0..3, wave-uniform
    const int l     = l0 + ll;

    float acc[32];
    #pragma unroll
    for (int j = 0; j < 32; ++j) acc[j] = 0.f;

    const float4* ap = (const float4*)(self_attn + (size_t)n * M_ * EMB_ + chunk * 32);
    for (int m = 0; m < M_; ++m) {
        float dw = dltw[ll][m];
        const float4* a = ap + (size_t)m * (EMB_ / 4);
        #pragma unroll
        for (int j = 0; j < 8; ++j) {
            float4 av = a[j];
            acc[4 * j + 0] += av.x * dw;
            acc[4 * j + 1] += av.y * dw;
            acc[4 * j + 2] += av.z * dw;
            acc[4 * j + 3] += av.w * dw;
        }
    }

    // ---- Epilogue: dot with emb_cand[l] = emb_table[l+1], then 4-way cross-chunk reduce ----
    float part = 0.f;
    if (l < L_) {
        const float4* e = (const float4*)(emb_table + (size_t)(l + 1) * EMB_ + chunk * 32);
        #pragma unroll
        for (int j = 0; j < 8; ++j) {
            float4 ev = e[j];
            part += ev.x * acc[4 * j + 0] + ev.y * acc[4 * j + 1]
                  + ev.z * acc[4 * j + 2] + ev.w * acc[4 * j + 3];
        }
    }
    red[chunk][ll] = part;
    __syncthreads();

    if (tid < TL) {
        float r = red[0][tid] + red[1][tid] + red[2][tid] + red[3][tid];
        int lg = l0 + tid;
        if (lg < L_) out[(size_t)n * L_ + lg] = r;
    }
}

extern "C" void kernel_launch(void* const* d_in, const int* in_sizes, int n_in,
                              void* d_out, int out_size, void* d_ws, size_t ws_size,
                              hipStream_t stream) {
    const float* self_attn  = (const float*)d_in[0];
    const float* self_delta = (const float*)d_in[1];
    // d_in[2] = traj_len (int32) — unused by the reference computation
    const float* emb_table  = (const float*)d_in[3];
    const float* value_w    = (const float*)d_in[4];
    float* out = (float*)d_out;

    dim3 grid((L_ + TL - 1) / TL, N_);
    attn_fused_kernel<<<grid, NT, 0, stream>>>(self_attn, self_delta, emb_table, value_w, out);
}

// Round 2
// 455.703 us; speedup vs baseline: 1.2758x; 1.2758x over previous
//
#include <hip/hip_runtime.h>

#define N_   16
#define M_   100
#define L_   10000
#define EMB_ 128
#define TL   64    // l-tile per block
#define NT   256   // threads per block (4 waves)

__global__ __launch_bounds__(NT, 2) void attn_fused_kernel(
    const float* __restrict__ self_attn,   // (N, M, EMB)
    const float* __restrict__ self_delta,  // (N, M, L, 4)
    const float* __restrict__ emb_table,   // (L+1, EMB)
    const float* __restrict__ value_w,     // (M)
    float* __restrict__ out)               // (N, L)
{
    // dltw[ll][m] = (sum_d4 self_delta[n][m][l0+ll][d4]) * value_w[m]
    // stride 101 (odd): phase-1 store bank = (5*ll)%32 -> 2-way = free;
    // phase-2 read dltw[ll][m] lanes vary ll -> same 2-way = free.
    __shared__ float dltw[TL][M_ + 1];
    __shared__ float4 attn_s[M_ * EMB_ / 4];   // 100x128 fp32 = 51.2 KB, flat
    __shared__ float red[4][TL];
    __shared__ float wsh[M_];

    const int n   = blockIdx.y;
    const int l0  = blockIdx.x * TL;
    const int tid = threadIdx.x;

    if (tid < M_) wsh[tid] = value_w[tid];

    // ---- Stage attn panel into LDS (L2-hot after first round; 3200 float4) ----
    const float4* ga = (const float4*)(self_attn + (size_t)n * M_ * EMB_);
    for (int i = tid; i < M_ * EMB_ / 4; i += NT) {
        attn_s[i] = ga[i];
    }
    __syncthreads();   // wsh ready (needed by phase 1 below)

    // ---- Phase 1: stage delta*w into LDS (coalesced float4 HBM reads) ----
    const float4* dp = (const float4*)self_delta + (size_t)n * M_ * L_;
    #pragma unroll 5
    for (int it = 0; it < (TL * M_) / NT; ++it) {
        int idx = tid + it * NT;
        int ll  = idx & (TL - 1);
        int m   = idx >> 6;        // wave-uniform
        int l   = l0 + ll;
        float v = 0.f;
        if (l < L_) {
            float4 d4 = dp[(size_t)m * L_ + l];
            v = (d4.x + d4.y + d4.z + d4.w) * wsh[m];
        }
        dltw[ll][m] = v;
    }
    __syncthreads();

    // ---- Phase 2: q[d] = sum_m attn[m][d] * dltw[ll][m]; d-chunk of 32 per thread ----
    const int ll    = tid & (TL - 1);
    const int chunk = tid >> 6;    // 0..3, wave-uniform
    const int l     = l0 + ll;

    float acc[32];
    #pragma unroll
    for (int j = 0; j < 32; ++j) acc[j] = 0.f;

    const float4* as = attn_s + chunk * 8;   // wave-uniform base
    #pragma unroll 2
    for (int m = 0; m < M_; ++m) {
        float dw = dltw[ll][m];
        const float4* a = as + m * (EMB_ / 4);   // wave-uniform -> broadcast ds_read
        #pragma unroll
        for (int j = 0; j < 8; ++j) {
            float4 av = a[j];
            acc[4 * j + 0] += av.x * dw;
            acc[4 * j + 1] += av.y * dw;
            acc[4 * j + 2] += av.z * dw;
            acc[4 * j + 3] += av.w * dw;
        }
    }

    // ---- Epilogue: dot with emb_table[l+1], 4-way cross-chunk reduce ----
    float part = 0.f;
    if (l < L_) {
        const float4* e = (const float4*)(emb_table + (size_t)(l + 1) * EMB_ + chunk * 32);
        #pragma unroll
        for (int j = 0; j < 8; ++j) {
            float4 ev = e[j];
            part += ev.x * acc[4 * j + 0] + ev.y * acc[4 * j + 1]
                  + ev.z * acc[4 * j + 2] + ev.w * acc[4 * j + 3];
        }
    }
    red[chunk][ll] = part;
    __syncthreads();

    if (tid < TL) {
        float r = red[0][tid] + red[1][tid] + red[2][tid] + red[3][tid];
        int lg = l0 + tid;
        if (lg < L_) out[(size_t)n * L_ + lg] = r;
    }
}

extern "C" void kernel_launch(void* const* d_in, const int* in_sizes, int n_in,
                              void* d_out, int out_size, void* d_ws, size_t ws_size,
                              hipStream_t stream) {
    const float* self_attn  = (const float*)d_in[0];
    const float* self_delta = (const float*)d_in[1];
    // d_in[2] = traj_len (int32) — unused by the reference computation
    const float* emb_table  = (const float*)d_in[3];
    const float* value_w    = (const float*)d_in[4];
    float* out = (float*)d_out;

    dim3 grid((L_ + TL - 1) / TL, N_);
    attn_fused_kernel<<<grid, NT, 0, stream>>>(self_attn, self_delta, emb_table, value_w, out);
}

// Round 3
// 408.161 us; speedup vs baseline: 1.4244x; 1.1165x over previous
//
#include <hip/hip_runtime.h>

#define N_   16
#define M_   100
#define L_   10000
#define EMB_ 128
#define TL   64    // l-tile per block
#define NT   256   // threads per block (4 waves)

__global__ __launch_bounds__(NT, 5) void attn_fused_kernel(
    const float* __restrict__ self_attn,   // (N, M, EMB)
    const float* __restrict__ self_delta,  // (N, M, L, 4)
    const float* __restrict__ emb_table,   // (L+1, EMB)
    const float* __restrict__ value_w,     // (M)
    float* __restrict__ out)               // (N, L)
{
    // dltw[ll][m] = (sum_d4 self_delta[n][m][l0+ll][d4]) * value_w[m]
    // stride 101 (odd): phase-2 read dltw[ll][m] lanes vary ll -> 5*ll%32
    // bijective over 32 lanes -> 2-way across the wave = free (m136).
    __shared__ float dltw[TL][M_ + 1];
    __shared__ float red[4][TL];
    __shared__ float wsh[M_];

    const int n   = blockIdx.y;
    const int l0  = blockIdx.x * TL;
    const int tid = threadIdx.x;

    if (tid < M_) wsh[tid] = value_w[tid];
    __syncthreads();

    // ---- Phase 1: stage delta*w into LDS (coalesced float4 HBM reads) ----
    const float4* dp = (const float4*)self_delta + (size_t)n * M_ * L_;
    #pragma unroll 5
    for (int it = 0; it < (TL * M_) / NT; ++it) {
        int idx = tid + it * NT;
        int ll  = idx & (TL - 1);
        int m   = idx >> 6;        // wave-uniform
        int l   = l0 + ll;
        float v = 0.f;
        if (l < L_) {
            float4 d4 = dp[(size_t)m * L_ + l];
            v = (d4.x + d4.y + d4.z + d4.w) * wsh[m];
        }
        dltw[ll][m] = v;
    }
    __syncthreads();

    // ---- Phase 2: q[d] = sum_m attn[m][d] * dltw[ll][m]; 32-d chunk per thread ----
    // attn address is wave-uniform (blockIdx + readfirstlane(chunk) + m only)
    // -> compiler emits s_load_dwordx* into SGPRs via constant cache (L2-hot:
    // whole attn is 819 KB). FMA is v_fmac_f32 vdst, sgpr, vgpr — pure VALU,
    // zero LDS / vector-memory traffic for attn.
    const int ll    = tid & (TL - 1);
    const int chunk = __builtin_amdgcn_readfirstlane(tid >> 6);   // 0..3, forced uniform
    const int l     = l0 + ll;

    float acc[32];
    #pragma unroll
    for (int j = 0; j < 32; ++j) acc[j] = 0.f;

    const float* ap = self_attn + (size_t)n * M_ * EMB_ + chunk * 32;
    #pragma unroll 2
    for (int m = 0; m < M_; ++m) {
        float dw = dltw[ll][m];
        const float* a = ap + m * EMB_;   // uniform -> scalar loads
        #pragma unroll
        for (int j = 0; j < 32; ++j) {
            acc[j] += a[j] * dw;
        }
    }

    // ---- Epilogue: dot with emb_table[l+1], 4-way cross-chunk reduce ----
    float part = 0.f;
    if (l < L_) {
        const float4* e = (const float4*)(emb_table + (size_t)(l + 1) * EMB_ + chunk * 32);
        #pragma unroll
        for (int j = 0; j < 8; ++j) {
            float4 ev = e[j];
            part += ev.x * acc[4 * j + 0] + ev.y * acc[4 * j + 1]
                  + ev.z * acc[4 * j + 2] + ev.w * acc[4 * j + 3];
        }
    }
    red[chunk][ll] = part;
    __syncthreads();

    if (tid < TL) {
        float r = red[0][tid] + red[1][tid] + red[2][tid] + red[3][tid];
        int lg = l0 + tid;
        if (lg < L_) out[(size_t)n * L_ + lg] = r;
    }
}

extern "C" void kernel_launch(void* const* d_in, const int* in_sizes, int n_in,
                              void* d_out, int out_size, void* d_ws, size_t ws_size,
                              hipStream_t stream) {
    const float* self_attn  = (const float*)d_in[0];
    const float* self_delta = (const float*)d_in[1];
    // d_in[2] = traj_len (int32) — unused by the reference computation
    const float* emb_table  = (const float*)d_in[3];
    const float* value_w    = (const float*)d_in[4];
    float* out = (float*)d_out;

    dim3 grid((L_ + TL - 1) / TL, N_);
    attn_fused_kernel<<<grid, NT, 0, stream>>>(self_attn, self_delta, emb_table, value_w, out);
}